// Round 1
// baseline (257.512 us; speedup 1.0000x reference)
//
#include <hip/hip_runtime.h>
#include <hip/hip_bf16.h>
#include <math.h>

// Problem constants
#define B_  2
#define L_  2048
#define S_  2048
#define D_  256
#define H_  8
#define HD_ 32
#define ML_ (B_ * L_)
#define MS_ (B_ * S_)
#define NSPLIT 4
#define SCHUNK (S_ / NSPLIT)   // 512

typedef __attribute__((ext_vector_type(8))) short short8;   // 8 bf16 (A/B frag)
typedef __attribute__((ext_vector_type(4))) float f32x4;    // C/D frag

// ---------------------------------------------------------------------------
// One-shot fp32 -> bf16 conversion of all GEMM operands.
// ---------------------------------------------------------------------------
__global__ __launch_bounds__(256) void convert_all(
    const float* __restrict__ x,  const float* __restrict__ src,
    const float* __restrict__ Wq, const float* __restrict__ Wk,
    const float* __restrict__ Wv, const float* __restrict__ Wm,
    const float* __restrict__ W1, const float* __restrict__ W2,
    __hip_bfloat16* xb,  __hip_bfloat16* srcb,
    __hip_bfloat16* Wqb, __hip_bfloat16* Wkb,
    __hip_bfloat16* Wvb, __hip_bfloat16* Wmb,
    __hip_bfloat16* W1b, __hip_bfloat16* W2b) {
    const size_t i4 = ((size_t)blockIdx.x * 256 + threadIdx.x) * 4;
    const float* sp; __hip_bfloat16* dp; size_t off;
    if      (i4 < 1048576) { sp = x;   dp = xb;   off = i4; }
    else if (i4 < 2097152) { sp = src; dp = srcb; off = i4 - 1048576; }
    else if (i4 < 2162688) { sp = Wq;  dp = Wqb;  off = i4 - 2097152; }
    else if (i4 < 2228224) { sp = Wk;  dp = Wkb;  off = i4 - 2162688; }
    else if (i4 < 2293760) { sp = Wv;  dp = Wvb;  off = i4 - 2228224; }
    else if (i4 < 2359296) { sp = Wm;  dp = Wmb;  off = i4 - 2293760; }
    else if (i4 < 2621440) { sp = W1;  dp = W1b;  off = i4 - 2359296; }
    else                   { sp = W2;  dp = W2b;  off = i4 - 2621440; }
    float4 v = *(const float4*)(sp + off);
    __hip_bfloat16 o0 = __float2bfloat16(v.x), o1 = __float2bfloat16(v.y);
    __hip_bfloat16 o2 = __float2bfloat16(v.z), o3 = __float2bfloat16(v.w);
    __hip_bfloat16* d = dp + off;
    d[0] = o0; d[1] = o1; d[2] = o2; d[3] = o3;
}

// ---------------------------------------------------------------------------
// Shared bf16 MFMA GEMM body (64x64 tile, 4 waves). cscale in epilogue.
// ---------------------------------------------------------------------------
template <bool RELU, typename OutT>
__device__ __forceinline__ void gemm_body(const __hip_bfloat16* __restrict__ A,
                                          const __hip_bfloat16* __restrict__ A2,
                                          const __hip_bfloat16* __restrict__ Bm,
                                          OutT* __restrict__ C,
                                          int N, int K, int lda, int m0, int n0,
                                          float cscale,
                                          __hip_bfloat16 (&As)[64][72],
                                          __hip_bfloat16 (&Bs)[64][72]) {
    const int tid  = threadIdx.x;
    const int w    = tid >> 6;
    const int lane = tid & 63;
    const int colL = lane & 15;
    const int quad = lane >> 4;
    const int mh = (w & 1) * 32, nh = (w >> 1) * 32;
    const int srow = tid >> 3;
    const int scg  = (tid & 7) * 8;

    f32x4 acc[2][2] = {};

    auto loadA = [&](int p, int k0) -> short8 {
        const __hip_bfloat16* Asrc = A; int kk = k0;
        if (A2 && k0 >= 256) { Asrc = A2; kk = k0 - 256; }
        return *(const short8*)(Asrc + (size_t)(m0 + srow + p * 32) * lda + kk + scg);
    };
    auto loadB = [&](int p, int k0) -> short8 {
        return *(const short8*)(Bm + (size_t)(n0 + srow + p * 32) * K + k0 + scg);
    };

    short8 ra[2], rb[2];
#pragma unroll
    for (int p = 0; p < 2; ++p) { ra[p] = loadA(p, 0); rb[p] = loadB(p, 0); }

    for (int k0 = 0; k0 < K; k0 += 64) {
        __syncthreads();
#pragma unroll
        for (int p = 0; p < 2; ++p) {
            *(short8*)&As[srow + p * 32][scg] = ra[p];
            *(short8*)&Bs[srow + p * 32][scg] = rb[p];
        }
        __syncthreads();
        if (k0 + 64 < K) {
#pragma unroll
            for (int p = 0; p < 2; ++p) { ra[p] = loadA(p, k0 + 64); rb[p] = loadB(p, k0 + 64); }
        }
#pragma unroll
        for (int ks = 0; ks < 2; ++ks) {
            short8 af[2], bf[2];
#pragma unroll
            for (int i = 0; i < 2; ++i)
                af[i] = *(const short8*)&As[mh + i * 16 + colL][ks * 32 + quad * 8];
#pragma unroll
            for (int j = 0; j < 2; ++j)
                bf[j] = *(const short8*)&Bs[nh + j * 16 + colL][ks * 32 + quad * 8];
#pragma unroll
            for (int i = 0; i < 2; ++i)
#pragma unroll
                for (int j = 0; j < 2; ++j)
                    acc[i][j] = __builtin_amdgcn_mfma_f32_16x16x32_bf16(af[i], bf[j], acc[i][j], 0, 0, 0);
        }
    }
#pragma unroll
    for (int i = 0; i < 2; ++i)
#pragma unroll
        for (int r = 0; r < 4; ++r) {
            const size_t row = m0 + mh + i * 16 + quad * 4 + r;
#pragma unroll
            for (int j = 0; j < 2; ++j) {
                float v = acc[i][j][r] * cscale;
                if (RELU) v = fmaxf(v, 0.f);
                C[row * N + n0 + nh + j * 16 + colL] = (OutT)v;
            }
        }
}

// ---------------------------------------------------------------------------
// Fused Q/K/Vt projection GEMMs. Q is pre-scaled by 1/sqrt(hd)
// (the ONLY place the softmax scale is applied).
// Grid is 768 (r14 fix: previously 1024 launched 256 junk Vt blocks with
// b in {2,3} doing full GEMMs on garbage).
// ---------------------------------------------------------------------------
__global__ __launch_bounds__(256) void proj_fused(const __hip_bfloat16* __restrict__ x_b,
                                                  const __hip_bfloat16* __restrict__ src_b,
                                                  const __hip_bfloat16* __restrict__ Wq_b,
                                                  const __hip_bfloat16* __restrict__ Wk_b,
                                                  const __hip_bfloat16* __restrict__ Wv_b,
                                                  __hip_bfloat16* __restrict__ Qb,
                                                  __hip_bfloat16* __restrict__ Kb,
                                                  __hip_bfloat16* __restrict__ Vtb) {
    __shared__ __hip_bfloat16 As[64][72];
    __shared__ __hip_bfloat16 Bs[64][72];
    const int id = blockIdx.x;
    if (id < 256) {
        gemm_body<false, __hip_bfloat16>(x_b, nullptr, Wq_b, Qb, 256, 256, 256,
                                         (id >> 2) * 64, (id & 3) * 64,
                                         0.17677669529663687f, As, Bs);
    } else if (id < 512) {
        const int t = id - 256;
        gemm_body<false, __hip_bfloat16>(src_b, nullptr, Wk_b, Kb, 256, 256, 256,
                                         (t >> 2) * 64, (t & 3) * 64, 1.f, As, Bs);
    } else {
        const int t = id - 512;           // 0..255
        const int b = t >> 7, u = t & 127;
        gemm_body<false, __hip_bfloat16>(Wv_b, nullptr, src_b + (size_t)b * S_ * D_,
                                         Vtb + (size_t)b * D_ * S_, S_, 256, 256,
                                         (u & 3) * 64, (u >> 2) * 64, 1.f, As, Bs);
    }
}

// ---------------------------------------------------------------------------
// Flash attention — no online max, split-S, LDS-staged K/V, 128-wide S tiles.
// r14: 2 heads per block (blockIdx.y in [0,4)). attn_factor F is the largest
// memory stream (was 268 MB = 8x re-read across heads); pairing heads halves
// it, and h2=1's F loads re-hit L1/regs. LDS is XOR-swizzled (slot ^= row&7
// on 16B slots) instead of padded so the 2-head tile is EXACTLY 40960 B ->
// 4 blocks/CU, grid 1024 = one full residency round, no tail.
// ---------------------------------------------------------------------------
__global__ __launch_bounds__(256, 4) void attn_mfma(const __hip_bfloat16* __restrict__ Qb,
                                                    const __hip_bfloat16* __restrict__ Kb,
                                                    const __hip_bfloat16* __restrict__ Vtb,
                                                    const float* __restrict__ F,
                                                    __hip_bfloat16* __restrict__ Op,
                                                    float* __restrict__ Ll) {
    const int tid  = threadIdx.x;
    const int w    = tid >> 6;
    const int lane = tid & 63;
    const int colL = lane & 15;
    const int quad = lane >> 4;

    const int b     = blockIdx.z >> 2;
    const int split = blockIdx.z & 3;
    const int by    = blockIdx.y;          // head pair: heads by*2, by*2+1
    const int qw    = blockIdx.x * 64 + w * 16;

    // 16384 + 16384 + 8192 = 40960 B exactly -> 4 blocks/CU.
    __shared__ __hip_bfloat16 Ks[128][64];      // [s][2-head dims], swizzled
    __shared__ __hip_bfloat16 Vs[64][128];      // [2-head dims][s], swizzled
    __shared__ __hip_bfloat16 Pw[4][16][64];    // per-wave P tile, swizzled

    short8 aq2[2];
#pragma unroll
    for (int h2 = 0; h2 < 2; ++h2)
        aq2[h2] = *(const short8*)(Qb + ((size_t)(b * L_ + qw + colL)) * D_ +
                                   by * 64 + h2 * 32 + quad * 8);

    float lsum[2][4] = {};
    f32x4 o[2][2] = {};

    // K staging: 8 lanes/row cover 128 B (64 dims, both heads); 32 rows/pass.
    const int kr  = tid >> 3;          // 0..31
    const int kc8 = tid & 7;           // 16B slot within row
    // V staging: 4 lanes/row cover 32 s-elems; 64 dim-rows.
    const int vr  = tid >> 2;          // 0..63
    const int vc4 = tid & 3;           // 8-elem group within 32-s chunk
    const __hip_bfloat16* kst = Kb + ((size_t)(b * S_ + kr)) * D_ + by * 64 + kc8 * 8;
    const __hip_bfloat16* vst = Vtb + (size_t)b * D_ * S_ + ((size_t)(by * 64 + vr)) * S_ + vc4 * 8;
    const float* fbase = F + ((size_t)(b * L_ + qw + quad * 4)) * S_ + colL;

    const int sbeg = split * SCHUNK, send = sbeg + SCHUNK;
    short8 rk[4], rv[4];
#pragma unroll
    for (int p = 0; p < 4; ++p) {
        rk[p] = *(const short8*)(kst + (size_t)(sbeg + p * 32) * D_);
        rv[p] = *(const short8*)(vst + sbeg + p * 32);
    }

    for (int s0 = sbeg; s0 < send; s0 += 128) {
        __syncthreads();
#pragma unroll
        for (int p = 0; p < 4; ++p) {
            *(short8*)&Ks[p * 32 + kr][(kc8 ^ (kr & 7)) * 8]           = rk[p];
            *(short8*)&Vs[vr][((p * 4 + vc4) ^ (vr & 7)) * 8]          = rv[p];
        }
        __syncthreads();
        if (s0 + 128 < send) {
#pragma unroll
            for (int p = 0; p < 4; ++p) {
                rk[p] = *(const short8*)(kst + (size_t)(s0 + 128 + p * 32) * D_);
                rv[p] = *(const short8*)(vst + s0 + 128 + p * 32);
            }
        }
#pragma unroll
        for (int hs = 0; hs < 2; ++hs) {
            const int sh = s0 + hs * 64;
#pragma unroll
            for (int h2 = 0; h2 < 2; ++h2) {
                f32x4 cc[4];
#pragma unroll
                for (int n = 0; n < 4; ++n) {
                    short8 kf = *(const short8*)&Ks[hs * 64 + n * 16 + colL]
                                                  [((h2 * 4 + quad) ^ (colL & 7)) * 8];
                    f32x4 z = {0.f, 0.f, 0.f, 0.f};
                    cc[n] = __builtin_amdgcn_mfma_f32_16x16x32_bf16(aq2[h2], kf, z, 0, 0, 0);
                }
#pragma unroll
                for (int n = 0; n < 4; ++n)
#pragma unroll
                    for (int r = 0; r < 4; ++r) {
                        float fv = fbase[(size_t)r * S_ + sh + n * 16];
                        float p = __expf(cc[n][r] * fv);
                        lsum[h2][r] += p;
                        const int prow = quad * 4 + r;
                        Pw[w][prow][(n * 16 + colL) ^ ((prow & 7) << 3)] = __float2bfloat16(p);
                    }
                short8 a0 = *(const short8*)&Pw[w][colL][((0 + quad) ^ (colL & 7)) * 8];
                short8 a1 = *(const short8*)&Pw[w][colL][((4 + quad) ^ (colL & 7)) * 8];
#pragma unroll
                for (int ks = 0; ks < 2; ++ks) {
                    short8 ap = ks ? a1 : a0;
#pragma unroll
                    for (int nt = 0; nt < 2; ++nt) {
                        short8 vf = *(const short8*)&Vs[h2 * 32 + nt * 16 + colL]
                                                      [((hs * 8 + ks * 4 + quad) ^ (colL & 7)) * 8];
                        o[h2][nt] = __builtin_amdgcn_mfma_f32_16x16x32_bf16(ap, vf, o[h2][nt], 0, 0, 0);
                    }
                }
            }
        }
    }

#pragma unroll
    for (int h2 = 0; h2 < 2; ++h2)
#pragma unroll
        for (int r = 0; r < 4; ++r) {
            float t = lsum[h2][r];
            t += __shfl_xor(t, 1);
            t += __shfl_xor(t, 2);
            t += __shfl_xor(t, 4);
            t += __shfl_xor(t, 8);
            lsum[h2][r] = t;
        }

#pragma unroll
    for (int h2 = 0; h2 < 2; ++h2) {
        const int h = by * 2 + h2;
#pragma unroll
        for (int r = 0; r < 4; ++r) {
            const size_t row = (size_t)(b * L_ + qw + quad * 4 + r);
            const size_t po = ((size_t)split * ML_ + row) * D_ + h * HD_;
            Op[po + colL]      = __float2bfloat16(o[h2][0][r]);
            Op[po + 16 + colL] = __float2bfloat16(o[h2][1][r]);
            if (colL == 0)
                Ll[((size_t)split * H_ + h) * ML_ + row] = lsum[h2][r];
        }
    }
}

// ---------------------------------------------------------------------------
// MLP megakernel: per block 16 rows, three phases sharing LDS:
//   P1: combine Opart (+1/sumLl) -> Wm GEMM -> LN1 -> Acat[:,256:512]
//       (Acat[:,0:256] preloaded with x_b rows; A = [x | m1] for W1)
//   P2: W1 GEMM + ReLU over K=512 (A-frags from LDS Acat, B staged) -> Hs
//   P3: W2 GEMM over K=512 (A from Hs) + LN2 + residual -> out (fp32)
// Replaces 3 kernels; removes m1_b/h_b HBM round-trips.
// ---------------------------------------------------------------------------
__global__ __launch_bounds__(256) void mlp_fused(const __hip_bfloat16* __restrict__ Opart,
                                                 const float* __restrict__ Ll,
                                                 const __hip_bfloat16* __restrict__ x_b,
                                                 const __hip_bfloat16* __restrict__ Wm_b,
                                                 const __hip_bfloat16* __restrict__ W1_b,
                                                 const __hip_bfloat16* __restrict__ W2_b,
                                                 const float* __restrict__ g1,
                                                 const float* __restrict__ b1,
                                                 const float* __restrict__ g2,
                                                 const float* __restrict__ b2,
                                                 const float* __restrict__ x,
                                                 float* __restrict__ out) {
    __shared__ __hip_bfloat16 Bs[256][72];     // 36864 B (shared by all phases)
    __shared__ __hip_bfloat16 As[16][72];      // 2304 B  (phase-1 A staging)
    __shared__ __hip_bfloat16 Acat[16][520];   // 16640 B [x | m1]
    __shared__ __hip_bfloat16 Hs[16][520];     // 16640 B h (512 cols used)
    __shared__ float gs[256], bs_[256];
    __shared__ float stats[4][16][2];
    __shared__ float Linv[16][8];

    const int tid  = threadIdx.x;
    const int w    = tid >> 6;
    const int lane = tid & 63;
    const int colL = lane & 15;
    const int quad = lane >> 4;
    const int nh   = w * 64;
    const int m0   = blockIdx.x * 16;
    const int srow = tid >> 3;        // 0..31
    const int scg  = (tid & 7) * 8;   // 0..56

    // ---- phase 0: params, Linv, x rows -> Acat[:,0:256] ----
    gs[tid] = g1[tid]; bs_[tid] = b1[tid];
    if (tid < 128) {
        const int row = tid >> 3, hh = tid & 7;
        float t = 0.f;
#pragma unroll
        for (int s = 0; s < NSPLIT; ++s)
            t += Ll[((size_t)s * H_ + hh) * ML_ + m0 + row];
        Linv[row][hh] = 1.f / t;
    }
    {
        const int xr = tid >> 4, xc = (tid & 15) * 16;
        *(short8*)&Acat[xr][xc]     = *(const short8*)(x_b + (size_t)(m0 + xr) * 256 + xc);
        *(short8*)&Acat[xr][xc + 8] = *(const short8*)(x_b + (size_t)(m0 + xr) * 256 + xc + 8);
    }
    __syncthreads();

    // ---- phase 1: combine + Wm GEMM (K=256) ----
    f32x4 acc[4] = {};
    auto loadA1 = [&](int k0) -> short8 {     // srow < 16 only
        const float inv = Linv[srow][(k0 + scg) >> 5];
        float a[8] = {};
#pragma unroll
        for (int s = 0; s < NSPLIT; ++s) {
            short8 v = *(const short8*)(Opart + ((size_t)s * ML_ + m0 + srow) * 256 + k0 + scg);
#pragma unroll
            for (int e = 0; e < 8; ++e) {
                union { short s16; __hip_bfloat16 h; } c; c.s16 = v[e];
                a[e] += __bfloat162float(c.h);
            }
        }
        short8 outv;
#pragma unroll
        for (int e = 0; e < 8; ++e) {
            union { __hip_bfloat16 h; short s16; } c;
            c.h = __float2bfloat16(a[e] * inv);
            outv[e] = c.s16;
        }
        return outv;
    };

    {
        short8 ra = {};
        if (srow < 16) ra = loadA1(0);
        short8 rb[8];
#pragma unroll
        for (int p = 0; p < 8; ++p)
            rb[p] = *(const short8*)(Wm_b + (size_t)(srow + p * 32) * 256 + scg);
        for (int k0 = 0; k0 < 256; k0 += 64) {
            __syncthreads();
            if (srow < 16) *(short8*)&As[srow][scg] = ra;
#pragma unroll
            for (int p = 0; p < 8; ++p)
                *(short8*)&Bs[srow + p * 32][scg] = rb[p];
            __syncthreads();
            if (k0 + 64 < 256) {
                if (srow < 16) ra = loadA1(k0 + 64);
#pragma unroll
                for (int p = 0; p < 8; ++p)
                    rb[p] = *(const short8*)(Wm_b + (size_t)(srow + p * 32) * 256 + k0 + 64 + scg);
            }
#pragma unroll
            for (int ks = 0; ks < 2; ++ks) {
                short8 af = *(const short8*)&As[colL][ks * 32 + quad * 8];
#pragma unroll
                for (int j = 0; j < 4; ++j) {
                    short8 bf = *(const short8*)&Bs[nh + j * 16 + colL][ks * 32 + quad * 8];
                    acc[j] = __builtin_amdgcn_mfma_f32_16x16x32_bf16(af, bf, acc[j], 0, 0, 0);
                }
            }
        }
    }
    // LN1 stats + write m1 into Acat[:,256:512]
#pragma unroll
    for (int r = 0; r < 4; ++r) {
        float s = 0.f, q = 0.f;
#pragma unroll
        for (int j = 0; j < 4; ++j) { float v = acc[j][r]; s += v; q += v * v; }
        s += __shfl_xor(s, 1); q += __shfl_xor(q, 1);
        s += __shfl_xor(s, 2); q += __shfl_xor(q, 2);
        s += __shfl_xor(s, 4); q += __shfl_xor(q, 4);
        s += __shfl_xor(s, 8); q += __shfl_xor(q, 8);
        if (colL == 0) { stats[w][quad * 4 + r][0] = s; stats[w][quad * 4 + r][1] = q; }
    }
    __syncthreads();
#pragma unroll
    for (int r = 0; r < 4; ++r) {
        const int row = quad * 4 + r;
        const float S = stats[0][row][0] + stats[1][row][0] + stats[2][row][0] + stats[3][row][0];
        const float Q = stats[0][row][1] + stats[1][row][1] + stats[2][row][1] + stats[3][row][1];
        const float mean = S * (1.f / 256.f);
        const float rstd = rsqrtf(Q * (1.f / 256.f) - mean * mean + 1e-5f);
#pragma unroll
        for (int j = 0; j < 4; ++j) {
            const int col = nh + j * 16 + colL;
            Acat[row][256 + col] = __float2bfloat16((acc[j][r] - mean) * rstd * gs[col] + bs_[col]);
        }
    }
    __syncthreads();   // Acat complete; phase-1 gs reads done

    // ---- phase 2: W1 + ReLU (K=512, A from Acat), h -> Hs ----
#pragma unroll 1
    for (int nc = 0; nc < 2; ++nc) {
#pragma unroll
        for (int j = 0; j < 4; ++j) acc[j] = (f32x4){0.f, 0.f, 0.f, 0.f};
        short8 rb[8];
#pragma unroll
        for (int p = 0; p < 8; ++p)
            rb[p] = *(const short8*)(W1_b + (size_t)(nc * 256 + srow + p * 32) * 512 + scg);
        for (int k0 = 0; k0 < 512; k0 += 64) {
            __syncthreads();
#pragma unroll
            for (int p = 0; p < 8; ++p)
                *(short8*)&Bs[srow + p * 32][scg] = rb[p];
            __syncthreads();
            if (k0 + 64 < 512) {
#pragma unroll
                for (int p = 0; p < 8; ++p)
                    rb[p] = *(const short8*)(W1_b + (size_t)(nc * 256 + srow + p * 32) * 512 + k0 + 64 + scg);
            }
#pragma unroll
            for (int ks = 0; ks < 2; ++ks) {
                short8 af = *(const short8*)&Acat[colL][k0 + ks * 32 + quad * 8];
#pragma unroll
                for (int j = 0; j < 4; ++j) {
                    short8 bf = *(const short8*)&Bs[nh + j * 16 + colL][ks * 32 + quad * 8];
                    acc[j] = __builtin_amdgcn_mfma_f32_16x16x32_bf16(af, bf, acc[j], 0, 0, 0);
                }
            }
        }
#pragma unroll
        for (int r = 0; r < 4; ++r) {
            const int row = quad * 4 + r;
#pragma unroll
            for (int j = 0; j < 4; ++j) {
                const int col = nc * 256 + nh + j * 16 + colL;
                Hs[row][col] = __float2bfloat16(fmaxf(acc[j][r], 0.f));
            }
        }
    }
    gs[tid] = g2[tid]; bs_[tid] = b2[tid];   // safe: next barrier orders use
    __syncthreads();   // Hs complete

    // ---- phase 3: W2 (K=512, A from Hs) + LN2 + residual -> out ----
#pragma unroll
    for (int j = 0; j < 4; ++j) acc[j] = (f32x4){0.f, 0.f, 0.f, 0.f};
    {
        short8 rb[8];
#pragma unroll
        for (int p = 0; p < 8; ++p)
            rb[p] = *(const short8*)(W2_b + (size_t)(srow + p * 32) * 512 + scg);
        for (int k0 = 0; k0 < 512; k0 += 64) {
            __syncthreads();
#pragma unroll
            for (int p = 0; p < 8; ++p)
                *(short8*)&Bs[srow + p * 32][scg] = rb[p];
            __syncthreads();
            if (k0 + 64 < 512) {
#pragma unroll
                for (int p = 0; p < 8; ++p)
                    rb[p] = *(const short8*)(W2_b + (size_t)(srow + p * 32) * 512 + k0 + 64 + scg);
            }
#pragma unroll
            for (int ks = 0; ks < 2; ++ks) {
                short8 af = *(const short8*)&Hs[colL][k0 + ks * 32 + quad * 8];
#pragma unroll
                for (int j = 0; j < 4; ++j) {
                    short8 bf = *(const short8*)&Bs[nh + j * 16 + colL][ks * 32 + quad * 8];
                    acc[j] = __builtin_amdgcn_mfma_f32_16x16x32_bf16(af, bf, acc[j], 0, 0, 0);
                }
            }
        }
    }
#pragma unroll
    for (int r = 0; r < 4; ++r) {
        float s = 0.f, q = 0.f;
#pragma unroll
        for (int j = 0; j < 4; ++j) { float v = acc[j][r]; s += v; q += v * v; }
        s += __shfl_xor(s, 1); q += __shfl_xor(q, 1);
        s += __shfl_xor(s, 2); q += __shfl_xor(q, 2);
        s += __shfl_xor(s, 4); q += __shfl_xor(q, 4);
        s += __shfl_xor(s, 8); q += __shfl_xor(q, 8);
        if (colL == 0) { stats[w][quad * 4 + r][0] = s; stats[w][quad * 4 + r][1] = q; }
    }
    __syncthreads();
#pragma unroll
    for (int r = 0; r < 4; ++r) {
        const int row = quad * 4 + r;
        const float S = stats[0][row][0] + stats[1][row][0] + stats[2][row][0] + stats[3][row][0];
        const float Q = stats[0][row][1] + stats[1][row][1] + stats[2][row][1] + stats[3][row][1];
        const float mean = S * (1.f / 256.f);
        const float rstd = rsqrtf(Q * (1.f / 256.f) - mean * mean + 1e-5f);
        const size_t grow = (size_t)(m0 + row) * 256;
#pragma unroll
        for (int j = 0; j < 4; ++j) {
            const int col = nh + j * 16 + colL;
            out[grow + col] = (acc[j][r] - mean) * rstd * gs[col] + bs_[col] + x[grow + col];
        }
    }
}

// ---------------------------------------------------------------------------
extern "C" void kernel_launch(void* const* d_in, const int* in_sizes, int n_in,
                              void* d_out, int out_size, void* d_ws, size_t ws_size,
                              hipStream_t stream) {
    (void)in_sizes; (void)n_in; (void)out_size; (void)ws_size;
    const float* x   = (const float*)d_in[0];
    const float* src = (const float*)d_in[1];
    const float* F   = (const float*)d_in[2];
    const float* Wq  = (const float*)d_in[3];
    const float* Wk  = (const float*)d_in[4];
    const float* Wv  = (const float*)d_in[5];
    const float* Wm  = (const float*)d_in[6];
    const float* W1  = (const float*)d_in[7];
    const float* W2  = (const float*)d_in[8];
    const float* g1  = (const float*)d_in[9];
    const float* b1  = (const float*)d_in[10];
    const float* g2  = (const float*)d_in[11];
    const float* b2  = (const float*)d_in[12];
    float* out = (float*)d_out;

    // Workspace (24 MB):
    //   [0,2M) x_b  [2M,4M) src_b  [4M,5.25M) weights bf16
    //   [6M,8M) Qb  [8M,10M) Kb  [10M,12M) Vtb
    //   [14M,22M) Opart  [22M,22.5M) Ll
    char* ws = (char*)d_ws;
    __hip_bfloat16* x_b   = (__hip_bfloat16*)(ws);
    __hip_bfloat16* src_b = (__hip_bfloat16*)(ws + (2u << 20));
    __hip_bfloat16* Wq_b  = (__hip_bfloat16*)(ws + (4u << 20));
    __hip_bfloat16* Wk_b  = (__hip_bfloat16*)(ws + (4u << 20) + 131072);
    __hip_bfloat16* Wv_b  = (__hip_bfloat16*)(ws + (4u << 20) + 2 * 131072);
    __hip_bfloat16* Wm_b  = (__hip_bfloat16*)(ws + (4u << 20) + 3 * 131072);
    __hip_bfloat16* W1_b  = (__hip_bfloat16*)(ws + (4u << 20) + 4 * 131072);
    __hip_bfloat16* W2_b  = (__hip_bfloat16*)(ws + (4u << 20) + 4 * 131072 + 524288);
    __hip_bfloat16* Qb   = (__hip_bfloat16*)(ws + (6u << 20));
    __hip_bfloat16* Kb   = (__hip_bfloat16*)(ws + (8u << 20));
    __hip_bfloat16* Vtb  = (__hip_bfloat16*)(ws + (10u << 20));
    __hip_bfloat16* Opart = (__hip_bfloat16*)(ws + (14u << 20));
    float* Ll  = (float*)(ws + (22u << 20));

    dim3 blk(256);
    convert_all<<<dim3(2688), blk, 0, stream>>>(x, src, Wq, Wk, Wv, Wm, W1, W2,
                                                x_b, src_b, Wq_b, Wk_b, Wv_b, Wm_b, W1_b, W2_b);
    // Fused Q/K/Vt projections (Q pre-scaled by 1/sqrt(hd)); 768 real blocks
    proj_fused<<<dim3(768), blk, 0, stream>>>(x_b, src_b, Wq_b, Wk_b, Wv_b, Qb, Kb, Vtb);
    // Attention: split-S partials, 2 heads/block (F re-read halved),
    // XOR-swizzled 40 KB LDS -> 4 blocks/CU, grid = one full residency round
    attn_mfma<<<dim3(L_ / 64, H_ / 2, B_ * NSPLIT), blk, 0, stream>>>(Qb, Kb, Vtb, F, Opart, Ll);
    // Combine + Wm + LN1 + W1 + ReLU + W2 + LN2 + residual, one kernel
    mlp_fused<<<dim3(ML_ / 16), blk, 0, stream>>>(Opart, Ll, x_b, Wm_b, W1_b, W2_b,
                                                  g1, b1, g2, b2, x, out);
}

// Round 2
// 159.699 us; speedup vs baseline: 1.6125x; 1.6125x over previous
//
#include <hip/hip_runtime.h>
#include <hip/hip_bf16.h>
#include <math.h>

// Problem constants
#define B_  2
#define L_  2048
#define S_  2048
#define D_  256
#define H_  8
#define HD_ 32
#define ML_ (B_ * L_)
#define MS_ (B_ * S_)
#define NSPLIT 4
#define SCHUNK (S_ / NSPLIT)   // 512

typedef __attribute__((ext_vector_type(8))) short short8;   // 8 bf16 (A/B frag)
typedef __attribute__((ext_vector_type(4))) float f32x4;    // C/D frag

// ---------------------------------------------------------------------------
// One-shot fp32 -> bf16 conversion of all GEMM operands.
// ---------------------------------------------------------------------------
__global__ __launch_bounds__(256) void convert_all(
    const float* __restrict__ x,  const float* __restrict__ src,
    const float* __restrict__ Wq, const float* __restrict__ Wk,
    const float* __restrict__ Wv, const float* __restrict__ Wm,
    const float* __restrict__ W1, const float* __restrict__ W2,
    __hip_bfloat16* xb,  __hip_bfloat16* srcb,
    __hip_bfloat16* Wqb, __hip_bfloat16* Wkb,
    __hip_bfloat16* Wvb, __hip_bfloat16* Wmb,
    __hip_bfloat16* W1b, __hip_bfloat16* W2b) {
    const size_t i4 = ((size_t)blockIdx.x * 256 + threadIdx.x) * 4;
    const float* sp; __hip_bfloat16* dp; size_t off;
    if      (i4 < 1048576) { sp = x;   dp = xb;   off = i4; }
    else if (i4 < 2097152) { sp = src; dp = srcb; off = i4 - 1048576; }
    else if (i4 < 2162688) { sp = Wq;  dp = Wqb;  off = i4 - 2097152; }
    else if (i4 < 2228224) { sp = Wk;  dp = Wkb;  off = i4 - 2162688; }
    else if (i4 < 2293760) { sp = Wv;  dp = Wvb;  off = i4 - 2228224; }
    else if (i4 < 2359296) { sp = Wm;  dp = Wmb;  off = i4 - 2293760; }
    else if (i4 < 2621440) { sp = W1;  dp = W1b;  off = i4 - 2359296; }
    else                   { sp = W2;  dp = W2b;  off = i4 - 2621440; }
    float4 v = *(const float4*)(sp + off);
    __hip_bfloat16 o0 = __float2bfloat16(v.x), o1 = __float2bfloat16(v.y);
    __hip_bfloat16 o2 = __float2bfloat16(v.z), o3 = __float2bfloat16(v.w);
    __hip_bfloat16* d = dp + off;
    d[0] = o0; d[1] = o1; d[2] = o2; d[3] = o3;
}

// ---------------------------------------------------------------------------
// Shared bf16 MFMA GEMM body (64x64 tile, 4 waves). cscale in epilogue.
// ---------------------------------------------------------------------------
template <bool RELU, typename OutT>
__device__ __forceinline__ void gemm_body(const __hip_bfloat16* __restrict__ A,
                                          const __hip_bfloat16* __restrict__ A2,
                                          const __hip_bfloat16* __restrict__ Bm,
                                          OutT* __restrict__ C,
                                          int N, int K, int lda, int m0, int n0,
                                          float cscale,
                                          __hip_bfloat16 (&As)[64][72],
                                          __hip_bfloat16 (&Bs)[64][72]) {
    const int tid  = threadIdx.x;
    const int w    = tid >> 6;
    const int lane = tid & 63;
    const int colL = lane & 15;
    const int quad = lane >> 4;
    const int mh = (w & 1) * 32, nh = (w >> 1) * 32;
    const int srow = tid >> 3;
    const int scg  = (tid & 7) * 8;

    f32x4 acc[2][2] = {};

    auto loadA = [&](int p, int k0) -> short8 {
        const __hip_bfloat16* Asrc = A; int kk = k0;
        if (A2 && k0 >= 256) { Asrc = A2; kk = k0 - 256; }
        return *(const short8*)(Asrc + (size_t)(m0 + srow + p * 32) * lda + kk + scg);
    };
    auto loadB = [&](int p, int k0) -> short8 {
        return *(const short8*)(Bm + (size_t)(n0 + srow + p * 32) * K + k0 + scg);
    };

    short8 ra[2], rb[2];
#pragma unroll
    for (int p = 0; p < 2; ++p) { ra[p] = loadA(p, 0); rb[p] = loadB(p, 0); }

    for (int k0 = 0; k0 < K; k0 += 64) {
        __syncthreads();
#pragma unroll
        for (int p = 0; p < 2; ++p) {
            *(short8*)&As[srow + p * 32][scg] = ra[p];
            *(short8*)&Bs[srow + p * 32][scg] = rb[p];
        }
        __syncthreads();
        if (k0 + 64 < K) {
#pragma unroll
            for (int p = 0; p < 2; ++p) { ra[p] = loadA(p, k0 + 64); rb[p] = loadB(p, k0 + 64); }
        }
#pragma unroll
        for (int ks = 0; ks < 2; ++ks) {
            short8 af[2], bf[2];
#pragma unroll
            for (int i = 0; i < 2; ++i)
                af[i] = *(const short8*)&As[mh + i * 16 + colL][ks * 32 + quad * 8];
#pragma unroll
            for (int j = 0; j < 2; ++j)
                bf[j] = *(const short8*)&Bs[nh + j * 16 + colL][ks * 32 + quad * 8];
#pragma unroll
            for (int i = 0; i < 2; ++i)
#pragma unroll
                for (int j = 0; j < 2; ++j)
                    acc[i][j] = __builtin_amdgcn_mfma_f32_16x16x32_bf16(af[i], bf[j], acc[i][j], 0, 0, 0);
        }
    }
#pragma unroll
    for (int i = 0; i < 2; ++i)
#pragma unroll
        for (int r = 0; r < 4; ++r) {
            const size_t row = m0 + mh + i * 16 + quad * 4 + r;
#pragma unroll
            for (int j = 0; j < 2; ++j) {
                float v = acc[i][j][r] * cscale;
                if (RELU) v = fmaxf(v, 0.f);
                C[row * N + n0 + nh + j * 16 + colL] = (OutT)v;
            }
        }
}

// ---------------------------------------------------------------------------
// Fused Q/K/Vt projection GEMMs. Q is pre-scaled by 1/sqrt(hd)
// (the ONLY place the softmax scale is applied).
// Grid is 768: previously 1024 launched 256 junk Vt blocks (b in {2,3}, B_=2)
// doing full 64x64x256 GEMMs on garbage -> ~25% of proj time wasted.
// ---------------------------------------------------------------------------
__global__ __launch_bounds__(256) void proj_fused(const __hip_bfloat16* __restrict__ x_b,
                                                  const __hip_bfloat16* __restrict__ src_b,
                                                  const __hip_bfloat16* __restrict__ Wq_b,
                                                  const __hip_bfloat16* __restrict__ Wk_b,
                                                  const __hip_bfloat16* __restrict__ Wv_b,
                                                  __hip_bfloat16* __restrict__ Qb,
                                                  __hip_bfloat16* __restrict__ Kb,
                                                  __hip_bfloat16* __restrict__ Vtb) {
    __shared__ __hip_bfloat16 As[64][72];
    __shared__ __hip_bfloat16 Bs[64][72];
    const int id = blockIdx.x;
    if (id < 256) {
        gemm_body<false, __hip_bfloat16>(x_b, nullptr, Wq_b, Qb, 256, 256, 256,
                                         (id >> 2) * 64, (id & 3) * 64,
                                         0.17677669529663687f, As, Bs);
    } else if (id < 512) {
        const int t = id - 256;
        gemm_body<false, __hip_bfloat16>(src_b, nullptr, Wk_b, Kb, 256, 256, 256,
                                         (t >> 2) * 64, (t & 3) * 64, 1.f, As, Bs);
    } else {
        const int t = id - 512;           // 0..255 (grid 768: only real blocks)
        const int b = t >> 7, u = t & 127;
        gemm_body<false, __hip_bfloat16>(Wv_b, nullptr, src_b + (size_t)b * S_ * D_,
                                         Vtb + (size_t)b * D_ * S_, S_, 256, 256,
                                         (u & 3) * 64, (u >> 2) * 64, 1.f, As, Bs);
    }
}

// ---------------------------------------------------------------------------
// Flash attention — no online max, split-S, LDS-staged K/V, 128-wide S tiles.
// REVERTED to the round-0 proven version (161.5us session best). The r14
// head-pair variant (2 heads/block, 40KB XOR-swizzled LDS) regressed attn
// 135us: VGPR=64 budget serialized the per-tile scalar F loads (MfmaUtil
// 2.4%, VALUBusy 8.8%, all idle -> latency-bound), and 4x40960B left no
// margin for reserved LDS -> 3 blocks/CU + grid tail. F re-read across heads
// is absorbed by L2/L3 (F = 33.5MB << 256MB; attn FETCH was only 84MB), so
// per-head blocks with small live state win.
// ---------------------------------------------------------------------------
__global__ __launch_bounds__(256, 4) void attn_mfma(const __hip_bfloat16* __restrict__ Qb,
                                                    const __hip_bfloat16* __restrict__ Kb,
                                                    const __hip_bfloat16* __restrict__ Vtb,
                                                    const float* __restrict__ F,
                                                    __hip_bfloat16* __restrict__ Op,
                                                    float* __restrict__ Ll) {
    const int tid  = threadIdx.x;
    const int w    = tid >> 6;
    const int lane = tid & 63;
    const int colL = lane & 15;
    const int quad = lane >> 4;

    const int b     = blockIdx.z >> 2;
    const int split = blockIdx.z & 3;
    const int h     = blockIdx.y;
    const int qw    = blockIdx.x * 64 + w * 16;

    __shared__ __hip_bfloat16 Ks[128][40];
    __shared__ __hip_bfloat16 Vs[32][136];
    __shared__ __hip_bfloat16 Pw[4][16][72];

    const short8 aq = *(const short8*)(Qb + ((size_t)(b * L_ + qw + colL)) * D_ + h * HD_ + quad * 8);

    float lsum[4] = {0.f, 0.f, 0.f, 0.f};
    f32x4 o0 = {0.f, 0.f, 0.f, 0.f}, o1 = {0.f, 0.f, 0.f, 0.f};

    const int kr = tid >> 2, kc = (tid & 3) * 8;
    const int vr = tid >> 3, vc = (tid & 7) * 8;
    const __hip_bfloat16* kst = Kb + ((size_t)(b * S_ + kr)) * D_ + h * HD_ + kc;
    const __hip_bfloat16* vst = Vtb + (size_t)b * D_ * S_ + ((size_t)(h * HD_ + vr)) * S_ + vc;
    const float* fbase = F + ((size_t)(b * L_ + qw + quad * 4)) * S_ + colL;

    const int sbeg = split * SCHUNK, send = sbeg + SCHUNK;
    short8 rk[2], rv[2];
#pragma unroll
    for (int p = 0; p < 2; ++p) {
        rk[p] = *(const short8*)(kst + (size_t)(sbeg + p * 64) * D_);
        rv[p] = *(const short8*)(vst + sbeg + p * 64);
    }

    for (int s0 = sbeg; s0 < send; s0 += 128) {
        __syncthreads();
        *(short8*)&Ks[kr][kc]        = rk[0];
        *(short8*)&Ks[kr + 64][kc]   = rk[1];
        *(short8*)&Vs[vr][vc]        = rv[0];
        *(short8*)&Vs[vr][vc + 64]   = rv[1];
        __syncthreads();
        if (s0 + 128 < send) {
#pragma unroll
            for (int p = 0; p < 2; ++p) {
                rk[p] = *(const short8*)(kst + (size_t)(s0 + 128 + p * 64) * D_);
                rv[p] = *(const short8*)(vst + s0 + 128 + p * 64);
            }
        }
#pragma unroll
        for (int hs = 0; hs < 2; ++hs) {
            const int sh = s0 + hs * 64;
            f32x4 cc[4];
#pragma unroll
            for (int n = 0; n < 4; ++n) {
                short8 kf = *(const short8*)&Ks[hs * 64 + n * 16 + colL][quad * 8];
                f32x4 z = {0.f, 0.f, 0.f, 0.f};
                cc[n] = __builtin_amdgcn_mfma_f32_16x16x32_bf16(aq, kf, z, 0, 0, 0);
            }
#pragma unroll
            for (int n = 0; n < 4; ++n)
#pragma unroll
                for (int r = 0; r < 4; ++r) {
                    float fv = fbase[(size_t)r * S_ + sh + n * 16];
                    float p = __expf(cc[n][r] * fv);
                    lsum[r] += p;
                    Pw[w][quad * 4 + r][n * 16 + colL] = __float2bfloat16(p);
                }
            short8 a0 = *(const short8*)(&Pw[w][colL][quad * 8]);
            short8 a1 = *(const short8*)(&Pw[w][colL][32 + quad * 8]);
#pragma unroll
            for (int ks = 0; ks < 2; ++ks) {
                short8 ap = ks ? a1 : a0;
#pragma unroll
                for (int nt = 0; nt < 2; ++nt) {
                    short8 vf = *(const short8*)&Vs[nt * 16 + colL][hs * 64 + ks * 32 + quad * 8];
                    if (nt == 0) o0 = __builtin_amdgcn_mfma_f32_16x16x32_bf16(ap, vf, o0, 0, 0, 0);
                    else         o1 = __builtin_amdgcn_mfma_f32_16x16x32_bf16(ap, vf, o1, 0, 0, 0);
                }
            }
        }
    }

#pragma unroll
    for (int r = 0; r < 4; ++r) {
        float t = lsum[r];
        t += __shfl_xor(t, 1);
        t += __shfl_xor(t, 2);
        t += __shfl_xor(t, 4);
        t += __shfl_xor(t, 8);
        lsum[r] = t;
    }

#pragma unroll
    for (int r = 0; r < 4; ++r) {
        const size_t row = (size_t)(b * L_ + qw + quad * 4 + r);
        const size_t po = ((size_t)split * ML_ + row) * D_ + h * HD_;
        Op[po + colL]      = __float2bfloat16(o0[r]);
        Op[po + 16 + colL] = __float2bfloat16(o1[r]);
        if (colL == 0)
            Ll[((size_t)split * H_ + h) * ML_ + row] = lsum[r];
    }
}

// ---------------------------------------------------------------------------
// MLP megakernel: per block 16 rows, three phases sharing LDS:
//   P1: combine Opart (+1/sumLl) -> Wm GEMM -> LN1 -> Acat[:,256:512]
//       (Acat[:,0:256] preloaded with x_b rows; A = [x | m1] for W1)
//   P2: W1 GEMM + ReLU over K=512 (A-frags from LDS Acat, B staged) -> Hs
//   P3: W2 GEMM over K=512 (A from Hs) + LN2 + residual -> out (fp32)
// Replaces 3 kernels; removes m1_b/h_b HBM round-trips.
// ---------------------------------------------------------------------------
__global__ __launch_bounds__(256) void mlp_fused(const __hip_bfloat16* __restrict__ Opart,
                                                 const float* __restrict__ Ll,
                                                 const __hip_bfloat16* __restrict__ x_b,
                                                 const __hip_bfloat16* __restrict__ Wm_b,
                                                 const __hip_bfloat16* __restrict__ W1_b,
                                                 const __hip_bfloat16* __restrict__ W2_b,
                                                 const float* __restrict__ g1,
                                                 const float* __restrict__ b1,
                                                 const float* __restrict__ g2,
                                                 const float* __restrict__ b2,
                                                 const float* __restrict__ x,
                                                 float* __restrict__ out) {
    __shared__ __hip_bfloat16 Bs[256][72];     // 36864 B (shared by all phases)
    __shared__ __hip_bfloat16 As[16][72];      // 2304 B  (phase-1 A staging)
    __shared__ __hip_bfloat16 Acat[16][520];   // 16640 B [x | m1]
    __shared__ __hip_bfloat16 Hs[16][520];     // 16640 B h (512 cols used)
    __shared__ float gs[256], bs_[256];
    __shared__ float stats[4][16][2];
    __shared__ float Linv[16][8];

    const int tid  = threadIdx.x;
    const int w    = tid >> 6;
    const int lane = tid & 63;
    const int colL = lane & 15;
    const int quad = lane >> 4;
    const int nh   = w * 64;
    const int m0   = blockIdx.x * 16;
    const int srow = tid >> 3;        // 0..31
    const int scg  = (tid & 7) * 8;   // 0..56

    // ---- phase 0: params, Linv, x rows -> Acat[:,0:256] ----
    gs[tid] = g1[tid]; bs_[tid] = b1[tid];
    if (tid < 128) {
        const int row = tid >> 3, hh = tid & 7;
        float t = 0.f;
#pragma unroll
        for (int s = 0; s < NSPLIT; ++s)
            t += Ll[((size_t)s * H_ + hh) * ML_ + m0 + row];
        Linv[row][hh] = 1.f / t;
    }
    {
        const int xr = tid >> 4, xc = (tid & 15) * 16;
        *(short8*)&Acat[xr][xc]     = *(const short8*)(x_b + (size_t)(m0 + xr) * 256 + xc);
        *(short8*)&Acat[xr][xc + 8] = *(const short8*)(x_b + (size_t)(m0 + xr) * 256 + xc + 8);
    }
    __syncthreads();

    // ---- phase 1: combine + Wm GEMM (K=256) ----
    f32x4 acc[4] = {};
    auto loadA1 = [&](int k0) -> short8 {     // srow < 16 only
        const float inv = Linv[srow][(k0 + scg) >> 5];
        float a[8] = {};
#pragma unroll
        for (int s = 0; s < NSPLIT; ++s) {
            short8 v = *(const short8*)(Opart + ((size_t)s * ML_ + m0 + srow) * 256 + k0 + scg);
#pragma unroll
            for (int e = 0; e < 8; ++e) {
                union { short s16; __hip_bfloat16 h; } c; c.s16 = v[e];
                a[e] += __bfloat162float(c.h);
            }
        }
        short8 outv;
#pragma unroll
        for (int e = 0; e < 8; ++e) {
            union { __hip_bfloat16 h; short s16; } c;
            c.h = __float2bfloat16(a[e] * inv);
            outv[e] = c.s16;
        }
        return outv;
    };

    {
        short8 ra = {};
        if (srow < 16) ra = loadA1(0);
        short8 rb[8];
#pragma unroll
        for (int p = 0; p < 8; ++p)
            rb[p] = *(const short8*)(Wm_b + (size_t)(srow + p * 32) * 256 + scg);
        for (int k0 = 0; k0 < 256; k0 += 64) {
            __syncthreads();
            if (srow < 16) *(short8*)&As[srow][scg] = ra;
#pragma unroll
            for (int p = 0; p < 8; ++p)
                *(short8*)&Bs[srow + p * 32][scg] = rb[p];
            __syncthreads();
            if (k0 + 64 < 256) {
                if (srow < 16) ra = loadA1(k0 + 64);
#pragma unroll
                for (int p = 0; p < 8; ++p)
                    rb[p] = *(const short8*)(Wm_b + (size_t)(srow + p * 32) * 256 + k0 + 64 + scg);
            }
#pragma unroll
            for (int ks = 0; ks < 2; ++ks) {
                short8 af = *(const short8*)&As[colL][ks * 32 + quad * 8];
#pragma unroll
                for (int j = 0; j < 4; ++j) {
                    short8 bf = *(const short8*)&Bs[nh + j * 16 + colL][ks * 32 + quad * 8];
                    acc[j] = __builtin_amdgcn_mfma_f32_16x16x32_bf16(af, bf, acc[j], 0, 0, 0);
                }
            }
        }
    }
    // LN1 stats + write m1 into Acat[:,256:512]
#pragma unroll
    for (int r = 0; r < 4; ++r) {
        float s = 0.f, q = 0.f;
#pragma unroll
        for (int j = 0; j < 4; ++j) { float v = acc[j][r]; s += v; q += v * v; }
        s += __shfl_xor(s, 1); q += __shfl_xor(q, 1);
        s += __shfl_xor(s, 2); q += __shfl_xor(q, 2);
        s += __shfl_xor(s, 4); q += __shfl_xor(q, 4);
        s += __shfl_xor(s, 8); q += __shfl_xor(q, 8);
        if (colL == 0) { stats[w][quad * 4 + r][0] = s; stats[w][quad * 4 + r][1] = q; }
    }
    __syncthreads();
#pragma unroll
    for (int r = 0; r < 4; ++r) {
        const int row = quad * 4 + r;
        const float S = stats[0][row][0] + stats[1][row][0] + stats[2][row][0] + stats[3][row][0];
        const float Q = stats[0][row][1] + stats[1][row][1] + stats[2][row][1] + stats[3][row][1];
        const float mean = S * (1.f / 256.f);
        const float rstd = rsqrtf(Q * (1.f / 256.f) - mean * mean + 1e-5f);
#pragma unroll
        for (int j = 0; j < 4; ++j) {
            const int col = nh + j * 16 + colL;
            Acat[row][256 + col] = __float2bfloat16((acc[j][r] - mean) * rstd * gs[col] + bs_[col]);
        }
    }
    __syncthreads();   // Acat complete; phase-1 gs reads done

    // ---- phase 2: W1 + ReLU (K=512, A from Acat), h -> Hs ----
#pragma unroll 1
    for (int nc = 0; nc < 2; ++nc) {
#pragma unroll
        for (int j = 0; j < 4; ++j) acc[j] = (f32x4){0.f, 0.f, 0.f, 0.f};
        short8 rb[8];
#pragma unroll
        for (int p = 0; p < 8; ++p)
            rb[p] = *(const short8*)(W1_b + (size_t)(nc * 256 + srow + p * 32) * 512 + scg);
        for (int k0 = 0; k0 < 512; k0 += 64) {
            __syncthreads();
#pragma unroll
            for (int p = 0; p < 8; ++p)
                *(short8*)&Bs[srow + p * 32][scg] = rb[p];
            __syncthreads();
            if (k0 + 64 < 512) {
#pragma unroll
                for (int p = 0; p < 8; ++p)
                    rb[p] = *(const short8*)(W1_b + (size_t)(nc * 256 + srow + p * 32) * 512 + k0 + 64 + scg);
            }
#pragma unroll
            for (int ks = 0; ks < 2; ++ks) {
                short8 af = *(const short8*)&Acat[colL][k0 + ks * 32 + quad * 8];
#pragma unroll
                for (int j = 0; j < 4; ++j) {
                    short8 bf = *(const short8*)&Bs[nh + j * 16 + colL][ks * 32 + quad * 8];
                    acc[j] = __builtin_amdgcn_mfma_f32_16x16x32_bf16(af, bf, acc[j], 0, 0, 0);
                }
            }
        }
#pragma unroll
        for (int r = 0; r < 4; ++r) {
            const int row = quad * 4 + r;
#pragma unroll
            for (int j = 0; j < 4; ++j) {
                const int col = nc * 256 + nh + j * 16 + colL;
                Hs[row][col] = __float2bfloat16(fmaxf(acc[j][r], 0.f));
            }
        }
    }
    gs[tid] = g2[tid]; bs_[tid] = b2[tid];   // safe: next barrier orders use
    __syncthreads();   // Hs complete

    // ---- phase 3: W2 (K=512, A from Hs) + LN2 + residual -> out ----
#pragma unroll
    for (int j = 0; j < 4; ++j) acc[j] = (f32x4){0.f, 0.f, 0.f, 0.f};
    {
        short8 rb[8];
#pragma unroll
        for (int p = 0; p < 8; ++p)
            rb[p] = *(const short8*)(W2_b + (size_t)(srow + p * 32) * 512 + scg);
        for (int k0 = 0; k0 < 512; k0 += 64) {
            __syncthreads();
#pragma unroll
            for (int p = 0; p < 8; ++p)
                *(short8*)&Bs[srow + p * 32][scg] = rb[p];
            __syncthreads();
            if (k0 + 64 < 512) {
#pragma unroll
                for (int p = 0; p < 8; ++p)
                    rb[p] = *(const short8*)(W2_b + (size_t)(srow + p * 32) * 512 + k0 + 64 + scg);
            }
#pragma unroll
            for (int ks = 0; ks < 2; ++ks) {
                short8 af = *(const short8*)&Hs[colL][k0 + ks * 32 + quad * 8];
#pragma unroll
                for (int j = 0; j < 4; ++j) {
                    short8 bf = *(const short8*)&Bs[nh + j * 16 + colL][ks * 32 + quad * 8];
                    acc[j] = __builtin_amdgcn_mfma_f32_16x16x32_bf16(af, bf, acc[j], 0, 0, 0);
                }
            }
        }
    }
#pragma unroll
    for (int r = 0; r < 4; ++r) {
        float s = 0.f, q = 0.f;
#pragma unroll
        for (int j = 0; j < 4; ++j) { float v = acc[j][r]; s += v; q += v * v; }
        s += __shfl_xor(s, 1); q += __shfl_xor(q, 1);
        s += __shfl_xor(s, 2); q += __shfl_xor(q, 2);
        s += __shfl_xor(s, 4); q += __shfl_xor(q, 4);
        s += __shfl_xor(s, 8); q += __shfl_xor(q, 8);
        if (colL == 0) { stats[w][quad * 4 + r][0] = s; stats[w][quad * 4 + r][1] = q; }
    }
    __syncthreads();
#pragma unroll
    for (int r = 0; r < 4; ++r) {
        const int row = quad * 4 + r;
        const float S = stats[0][row][0] + stats[1][row][0] + stats[2][row][0] + stats[3][row][0];
        const float Q = stats[0][row][1] + stats[1][row][1] + stats[2][row][1] + stats[3][row][1];
        const float mean = S * (1.f / 256.f);
        const float rstd = rsqrtf(Q * (1.f / 256.f) - mean * mean + 1e-5f);
        const size_t grow = (size_t)(m0 + row) * 256;
#pragma unroll
        for (int j = 0; j < 4; ++j) {
            const int col = nh + j * 16 + colL;
            out[grow + col] = (acc[j][r] - mean) * rstd * gs[col] + bs_[col] + x[grow + col];
        }
    }
}

// ---------------------------------------------------------------------------
extern "C" void kernel_launch(void* const* d_in, const int* in_sizes, int n_in,
                              void* d_out, int out_size, void* d_ws, size_t ws_size,
                              hipStream_t stream) {
    (void)in_sizes; (void)n_in; (void)out_size; (void)ws_size;
    const float* x   = (const float*)d_in[0];
    const float* src = (const float*)d_in[1];
    const float* F   = (const float*)d_in[2];
    const float* Wq  = (const float*)d_in[3];
    const float* Wk  = (const float*)d_in[4];
    const float* Wv  = (const float*)d_in[5];
    const float* Wm  = (const float*)d_in[6];
    const float* W1  = (const float*)d_in[7];
    const float* W2  = (const float*)d_in[8];
    const float* g1  = (const float*)d_in[9];
    const float* b1  = (const float*)d_in[10];
    const float* g2  = (const float*)d_in[11];
    const float* b2  = (const float*)d_in[12];
    float* out = (float*)d_out;

    // Workspace (24 MB):
    //   [0,2M) x_b  [2M,4M) src_b  [4M,5.25M) weights bf16
    //   [6M,8M) Qb  [8M,10M) Kb  [10M,12M) Vtb
    //   [14M,22M) Opart  [22M,22.5M) Ll
    char* ws = (char*)d_ws;
    __hip_bfloat16* x_b   = (__hip_bfloat16*)(ws);
    __hip_bfloat16* src_b = (__hip_bfloat16*)(ws + (2u << 20));
    __hip_bfloat16* Wq_b  = (__hip_bfloat16*)(ws + (4u << 20));
    __hip_bfloat16* Wk_b  = (__hip_bfloat16*)(ws + (4u << 20) + 131072);
    __hip_bfloat16* Wv_b  = (__hip_bfloat16*)(ws + (4u << 20) + 2 * 131072);
    __hip_bfloat16* Wm_b  = (__hip_bfloat16*)(ws + (4u << 20) + 3 * 131072);
    __hip_bfloat16* W1_b  = (__hip_bfloat16*)(ws + (4u << 20) + 4 * 131072);
    __hip_bfloat16* W2_b  = (__hip_bfloat16*)(ws + (4u << 20) + 4 * 131072 + 524288);
    __hip_bfloat16* Qb   = (__hip_bfloat16*)(ws + (6u << 20));
    __hip_bfloat16* Kb   = (__hip_bfloat16*)(ws + (8u << 20));
    __hip_bfloat16* Vtb  = (__hip_bfloat16*)(ws + (10u << 20));
    __hip_bfloat16* Opart = (__hip_bfloat16*)(ws + (14u << 20));
    float* Ll  = (float*)(ws + (22u << 20));

    dim3 blk(256);
    convert_all<<<dim3(2688), blk, 0, stream>>>(x, src, Wq, Wk, Wv, Wm, W1, W2,
                                                x_b, src_b, Wq_b, Wk_b, Wv_b, Wm_b, W1_b, W2_b);
    // Fused Q/K/Vt projections (Q pre-scaled by 1/sqrt(hd)); 768 real blocks
    proj_fused<<<dim3(768), blk, 0, stream>>>(x_b, src_b, Wq_b, Wk_b, Wv_b, Qb, Kb, Vtb);
    // Attention: split-S partials (round-0 proven version: per-head blocks,
    // 28KB padded LDS, 5 blocks/CU)
    attn_mfma<<<dim3(L_ / 64, H_, B_ * NSPLIT), blk, 0, stream>>>(Qb, Kb, Vtb, F, Opart, Ll);
    // Combine + Wm + LN1 + W1 + ReLU + W2 + LN2 + residual, one kernel
    mlp_fused<<<dim3(ML_ / 16), blk, 0, stream>>>(Opart, Ll, x_b, Wm_b, W1_b, W2_b,
                                                  g1, b1, g2, b2, x, out);
}

// Round 3
// 159.035 us; speedup vs baseline: 1.6192x; 1.0042x over previous
//
#include <hip/hip_runtime.h>
#include <hip/hip_bf16.h>
#include <math.h>

// Problem constants
#define B_  2
#define L_  2048
#define S_  2048
#define D_  256
#define H_  8
#define HD_ 32
#define ML_ (B_ * L_)
#define MS_ (B_ * S_)
#define NSPLIT 4
#define SCHUNK (S_ / NSPLIT)   // 512

typedef __attribute__((ext_vector_type(8))) short short8;   // 8 bf16 (A/B frag)
typedef __attribute__((ext_vector_type(4))) float f32x4;    // C/D frag

// ---------------------------------------------------------------------------
// One-shot fp32 -> bf16 conversion of all GEMM operands.
// ---------------------------------------------------------------------------
__global__ __launch_bounds__(256) void convert_all(
    const float* __restrict__ x,  const float* __restrict__ src,
    const float* __restrict__ Wq, const float* __restrict__ Wk,
    const float* __restrict__ Wv, const float* __restrict__ Wm,
    const float* __restrict__ W1, const float* __restrict__ W2,
    __hip_bfloat16* xb,  __hip_bfloat16* srcb,
    __hip_bfloat16* Wqb, __hip_bfloat16* Wkb,
    __hip_bfloat16* Wvb, __hip_bfloat16* Wmb,
    __hip_bfloat16* W1b, __hip_bfloat16* W2b) {
    const size_t i4 = ((size_t)blockIdx.x * 256 + threadIdx.x) * 4;
    const float* sp; __hip_bfloat16* dp; size_t off;
    if      (i4 < 1048576) { sp = x;   dp = xb;   off = i4; }
    else if (i4 < 2097152) { sp = src; dp = srcb; off = i4 - 1048576; }
    else if (i4 < 2162688) { sp = Wq;  dp = Wqb;  off = i4 - 2097152; }
    else if (i4 < 2228224) { sp = Wk;  dp = Wkb;  off = i4 - 2162688; }
    else if (i4 < 2293760) { sp = Wv;  dp = Wvb;  off = i4 - 2228224; }
    else if (i4 < 2359296) { sp = Wm;  dp = Wmb;  off = i4 - 2293760; }
    else if (i4 < 2621440) { sp = W1;  dp = W1b;  off = i4 - 2359296; }
    else                   { sp = W2;  dp = W2b;  off = i4 - 2621440; }
    float4 v = *(const float4*)(sp + off);
    __hip_bfloat16 o0 = __float2bfloat16(v.x), o1 = __float2bfloat16(v.y);
    __hip_bfloat16 o2 = __float2bfloat16(v.z), o3 = __float2bfloat16(v.w);
    __hip_bfloat16* d = dp + off;
    d[0] = o0; d[1] = o1; d[2] = o2; d[3] = o3;
}

// ---------------------------------------------------------------------------
// Shared bf16 MFMA GEMM body (64x64 tile, 4 waves). cscale in epilogue.
// ---------------------------------------------------------------------------
template <bool RELU, typename OutT>
__device__ __forceinline__ void gemm_body(const __hip_bfloat16* __restrict__ A,
                                          const __hip_bfloat16* __restrict__ A2,
                                          const __hip_bfloat16* __restrict__ Bm,
                                          OutT* __restrict__ C,
                                          int N, int K, int lda, int m0, int n0,
                                          float cscale,
                                          __hip_bfloat16 (&As)[64][72],
                                          __hip_bfloat16 (&Bs)[64][72]) {
    const int tid  = threadIdx.x;
    const int w    = tid >> 6;
    const int lane = tid & 63;
    const int colL = lane & 15;
    const int quad = lane >> 4;
    const int mh = (w & 1) * 32, nh = (w >> 1) * 32;
    const int srow = tid >> 3;
    const int scg  = (tid & 7) * 8;

    f32x4 acc[2][2] = {};

    auto loadA = [&](int p, int k0) -> short8 {
        const __hip_bfloat16* Asrc = A; int kk = k0;
        if (A2 && k0 >= 256) { Asrc = A2; kk = k0 - 256; }
        return *(const short8*)(Asrc + (size_t)(m0 + srow + p * 32) * lda + kk + scg);
    };
    auto loadB = [&](int p, int k0) -> short8 {
        return *(const short8*)(Bm + (size_t)(n0 + srow + p * 32) * K + k0 + scg);
    };

    short8 ra[2], rb[2];
#pragma unroll
    for (int p = 0; p < 2; ++p) { ra[p] = loadA(p, 0); rb[p] = loadB(p, 0); }

    for (int k0 = 0; k0 < K; k0 += 64) {
        __syncthreads();
#pragma unroll
        for (int p = 0; p < 2; ++p) {
            *(short8*)&As[srow + p * 32][scg] = ra[p];
            *(short8*)&Bs[srow + p * 32][scg] = rb[p];
        }
        __syncthreads();
        if (k0 + 64 < K) {
#pragma unroll
            for (int p = 0; p < 2; ++p) { ra[p] = loadA(p, k0 + 64); rb[p] = loadB(p, k0 + 64); }
        }
#pragma unroll
        for (int ks = 0; ks < 2; ++ks) {
            short8 af[2], bf[2];
#pragma unroll
            for (int i = 0; i < 2; ++i)
                af[i] = *(const short8*)&As[mh + i * 16 + colL][ks * 32 + quad * 8];
#pragma unroll
            for (int j = 0; j < 2; ++j)
                bf[j] = *(const short8*)&Bs[nh + j * 16 + colL][ks * 32 + quad * 8];
#pragma unroll
            for (int i = 0; i < 2; ++i)
#pragma unroll
                for (int j = 0; j < 2; ++j)
                    acc[i][j] = __builtin_amdgcn_mfma_f32_16x16x32_bf16(af[i], bf[j], acc[i][j], 0, 0, 0);
        }
    }
#pragma unroll
    for (int i = 0; i < 2; ++i)
#pragma unroll
        for (int r = 0; r < 4; ++r) {
            const size_t row = m0 + mh + i * 16 + quad * 4 + r;
#pragma unroll
            for (int j = 0; j < 2; ++j) {
                float v = acc[i][j][r] * cscale;
                if (RELU) v = fmaxf(v, 0.f);
                C[row * N + n0 + nh + j * 16 + colL] = (OutT)v;
            }
        }
}

// ---------------------------------------------------------------------------
// Fused Q/K/Vt projection GEMMs. Q is pre-scaled by 1/sqrt(hd)
// (the ONLY place the softmax scale is applied). Grid 768 (no junk blocks).
// ---------------------------------------------------------------------------
__global__ __launch_bounds__(256) void proj_fused(const __hip_bfloat16* __restrict__ x_b,
                                                  const __hip_bfloat16* __restrict__ src_b,
                                                  const __hip_bfloat16* __restrict__ Wq_b,
                                                  const __hip_bfloat16* __restrict__ Wk_b,
                                                  const __hip_bfloat16* __restrict__ Wv_b,
                                                  __hip_bfloat16* __restrict__ Qb,
                                                  __hip_bfloat16* __restrict__ Kb,
                                                  __hip_bfloat16* __restrict__ Vtb) {
    __shared__ __hip_bfloat16 As[64][72];
    __shared__ __hip_bfloat16 Bs[64][72];
    const int id = blockIdx.x;
    if (id < 256) {
        gemm_body<false, __hip_bfloat16>(x_b, nullptr, Wq_b, Qb, 256, 256, 256,
                                         (id >> 2) * 64, (id & 3) * 64,
                                         0.17677669529663687f, As, Bs);
    } else if (id < 512) {
        const int t = id - 256;
        gemm_body<false, __hip_bfloat16>(src_b, nullptr, Wk_b, Kb, 256, 256, 256,
                                         (t >> 2) * 64, (t & 3) * 64, 1.f, As, Bs);
    } else {
        const int t = id - 512;           // 0..255 (grid 768: only real blocks)
        const int b = t >> 7, u = t & 127;
        gemm_body<false, __hip_bfloat16>(Wv_b, nullptr, src_b + (size_t)b * S_ * D_,
                                         Vtb + (size_t)b * D_ * S_, S_, 256, 256,
                                         (u & 3) * 64, (u >> 2) * 64, 1.f, As, Bs);
    }
}

// ---------------------------------------------------------------------------
// Flash attention — round-0 proven version (per-head blocks, 28KB padded LDS,
// 5 blocks/CU). Do not touch: the r14 head-pair variant regressed 3.4x
// (latency-bound at VGPR=64; F re-read is L2/L3-absorbed, not HBM).
// ---------------------------------------------------------------------------
__global__ __launch_bounds__(256, 4) void attn_mfma(const __hip_bfloat16* __restrict__ Qb,
                                                    const __hip_bfloat16* __restrict__ Kb,
                                                    const __hip_bfloat16* __restrict__ Vtb,
                                                    const float* __restrict__ F,
                                                    __hip_bfloat16* __restrict__ Op,
                                                    float* __restrict__ Ll) {
    const int tid  = threadIdx.x;
    const int w    = tid >> 6;
    const int lane = tid & 63;
    const int colL = lane & 15;
    const int quad = lane >> 4;

    const int b     = blockIdx.z >> 2;
    const int split = blockIdx.z & 3;
    const int h     = blockIdx.y;
    const int qw    = blockIdx.x * 64 + w * 16;

    __shared__ __hip_bfloat16 Ks[128][40];
    __shared__ __hip_bfloat16 Vs[32][136];
    __shared__ __hip_bfloat16 Pw[4][16][72];

    const short8 aq = *(const short8*)(Qb + ((size_t)(b * L_ + qw + colL)) * D_ + h * HD_ + quad * 8);

    float lsum[4] = {0.f, 0.f, 0.f, 0.f};
    f32x4 o0 = {0.f, 0.f, 0.f, 0.f}, o1 = {0.f, 0.f, 0.f, 0.f};

    const int kr = tid >> 2, kc = (tid & 3) * 8;
    const int vr = tid >> 3, vc = (tid & 7) * 8;
    const __hip_bfloat16* kst = Kb + ((size_t)(b * S_ + kr)) * D_ + h * HD_ + kc;
    const __hip_bfloat16* vst = Vtb + (size_t)b * D_ * S_ + ((size_t)(h * HD_ + vr)) * S_ + vc;
    const float* fbase = F + ((size_t)(b * L_ + qw + quad * 4)) * S_ + colL;

    const int sbeg = split * SCHUNK, send = sbeg + SCHUNK;
    short8 rk[2], rv[2];
#pragma unroll
    for (int p = 0; p < 2; ++p) {
        rk[p] = *(const short8*)(kst + (size_t)(sbeg + p * 64) * D_);
        rv[p] = *(const short8*)(vst + sbeg + p * 64);
    }

    for (int s0 = sbeg; s0 < send; s0 += 128) {
        __syncthreads();
        *(short8*)&Ks[kr][kc]        = rk[0];
        *(short8*)&Ks[kr + 64][kc]   = rk[1];
        *(short8*)&Vs[vr][vc]        = rv[0];
        *(short8*)&Vs[vr][vc + 64]   = rv[1];
        __syncthreads();
        if (s0 + 128 < send) {
#pragma unroll
            for (int p = 0; p < 2; ++p) {
                rk[p] = *(const short8*)(kst + (size_t)(s0 + 128 + p * 64) * D_);
                rv[p] = *(const short8*)(vst + s0 + 128 + p * 64);
            }
        }
#pragma unroll
        for (int hs = 0; hs < 2; ++hs) {
            const int sh = s0 + hs * 64;
            f32x4 cc[4];
#pragma unroll
            for (int n = 0; n < 4; ++n) {
                short8 kf = *(const short8*)&Ks[hs * 64 + n * 16 + colL][quad * 8];
                f32x4 z = {0.f, 0.f, 0.f, 0.f};
                cc[n] = __builtin_amdgcn_mfma_f32_16x16x32_bf16(aq, kf, z, 0, 0, 0);
            }
#pragma unroll
            for (int n = 0; n < 4; ++n)
#pragma unroll
                for (int r = 0; r < 4; ++r) {
                    float fv = fbase[(size_t)r * S_ + sh + n * 16];
                    float p = __expf(cc[n][r] * fv);
                    lsum[r] += p;
                    Pw[w][quad * 4 + r][n * 16 + colL] = __float2bfloat16(p);
                }
            short8 a0 = *(const short8*)(&Pw[w][colL][quad * 8]);
            short8 a1 = *(const short8*)(&Pw[w][colL][32 + quad * 8]);
#pragma unroll
            for (int ks = 0; ks < 2; ++ks) {
                short8 ap = ks ? a1 : a0;
#pragma unroll
                for (int nt = 0; nt < 2; ++nt) {
                    short8 vf = *(const short8*)&Vs[nt * 16 + colL][hs * 64 + ks * 32 + quad * 8];
                    if (nt == 0) o0 = __builtin_amdgcn_mfma_f32_16x16x32_bf16(ap, vf, o0, 0, 0, 0);
                    else         o1 = __builtin_amdgcn_mfma_f32_16x16x32_bf16(ap, vf, o1, 0, 0, 0);
                }
            }
        }
    }

#pragma unroll
    for (int r = 0; r < 4; ++r) {
        float t = lsum[r];
        t += __shfl_xor(t, 1);
        t += __shfl_xor(t, 2);
        t += __shfl_xor(t, 4);
        t += __shfl_xor(t, 8);
        lsum[r] = t;
    }

#pragma unroll
    for (int r = 0; r < 4; ++r) {
        const size_t row = (size_t)(b * L_ + qw + quad * 4 + r);
        const size_t po = ((size_t)split * ML_ + row) * D_ + h * HD_;
        Op[po + colL]      = __float2bfloat16(o0[r]);
        Op[po + 16 + colL] = __float2bfloat16(o1[r]);
        if (colL == 0)
            Ll[((size_t)split * H_ + h) * ML_ + row] = lsum[r];
    }
}

// ---------------------------------------------------------------------------
// MLP megakernel, r15: 512 threads (8 waves) per block instead of 256.
// Grid is pinned at 256 blocks (16 rows x full-N ownership for the LN row
// reductions) = 1 block/CU, so occupancy must come from block size: 4 waves
// (1/SIMD, 12.5%) was too few to hide the staging latency between the 2
// barriers of each of the 28 K-steps. Now each wave owns a 32-col slice
// (j<2), per-wave MFMA work halves, waves/SIMD doubles. LDS layout and all
// row mappings unchanged; B staging uses p<4 stride-64 instead of p<8
// stride-32; stats widened to 8 waves; 256-wide param loads guarded.
// ---------------------------------------------------------------------------
__global__ __launch_bounds__(512) void mlp_fused(const __hip_bfloat16* __restrict__ Opart,
                                                 const float* __restrict__ Ll,
                                                 const __hip_bfloat16* __restrict__ x_b,
                                                 const __hip_bfloat16* __restrict__ Wm_b,
                                                 const __hip_bfloat16* __restrict__ W1_b,
                                                 const __hip_bfloat16* __restrict__ W2_b,
                                                 const float* __restrict__ g1,
                                                 const float* __restrict__ b1,
                                                 const float* __restrict__ g2,
                                                 const float* __restrict__ b2,
                                                 const float* __restrict__ x,
                                                 float* __restrict__ out) {
    __shared__ __hip_bfloat16 Bs[256][72];     // 36864 B (shared by all phases)
    __shared__ __hip_bfloat16 As[16][72];      // 2304 B  (phase-1 A staging)
    __shared__ __hip_bfloat16 Acat[16][520];   // 16640 B [x | m1]
    __shared__ __hip_bfloat16 Hs[16][520];     // 16640 B h (512 cols used)
    __shared__ float gs[256], bs_[256];
    __shared__ float stats[8][16][2];
    __shared__ float Linv[16][8];

    const int tid  = threadIdx.x;
    const int w    = tid >> 6;        // 0..7
    const int lane = tid & 63;
    const int colL = lane & 15;
    const int quad = lane >> 4;
    const int nh   = w * 32;          // per-wave 32-col slice
    const int m0   = blockIdx.x * 16;
    const int srow = tid >> 3;        // 0..63
    const int scg  = (tid & 7) * 8;   // 0..56

    // ---- phase 0: params, Linv, x rows -> Acat[:,0:256] ----
    if (tid < 256) { gs[tid] = g1[tid]; bs_[tid] = b1[tid]; }
    if (tid < 128) {
        const int row = tid >> 3, hh = tid & 7;
        float t = 0.f;
#pragma unroll
        for (int s = 0; s < NSPLIT; ++s)
            t += Ll[((size_t)s * H_ + hh) * ML_ + m0 + row];
        Linv[row][hh] = 1.f / t;
    }
    if (tid < 256) {
        const int xr = tid >> 4, xc = (tid & 15) * 16;
        *(short8*)&Acat[xr][xc]     = *(const short8*)(x_b + (size_t)(m0 + xr) * 256 + xc);
        *(short8*)&Acat[xr][xc + 8] = *(const short8*)(x_b + (size_t)(m0 + xr) * 256 + xc + 8);
    }
    __syncthreads();

    // ---- phase 1: combine + Wm GEMM (K=256) ----
    f32x4 acc[2] = {};
    auto loadA1 = [&](int k0) -> short8 {     // srow < 16 only (tid < 128)
        const float inv = Linv[srow][(k0 + scg) >> 5];
        float a[8] = {};
#pragma unroll
        for (int s = 0; s < NSPLIT; ++s) {
            short8 v = *(const short8*)(Opart + ((size_t)s * ML_ + m0 + srow) * 256 + k0 + scg);
#pragma unroll
            for (int e = 0; e < 8; ++e) {
                union { short s16; __hip_bfloat16 h; } c; c.s16 = v[e];
                a[e] += __bfloat162float(c.h);
            }
        }
        short8 outv;
#pragma unroll
        for (int e = 0; e < 8; ++e) {
            union { __hip_bfloat16 h; short s16; } c;
            c.h = __float2bfloat16(a[e] * inv);
            outv[e] = c.s16;
        }
        return outv;
    };

    {
        short8 ra = {};
        if (srow < 16) ra = loadA1(0);
        short8 rb[4];
#pragma unroll
        for (int p = 0; p < 4; ++p)
            rb[p] = *(const short8*)(Wm_b + (size_t)(srow + p * 64) * 256 + scg);
        for (int k0 = 0; k0 < 256; k0 += 64) {
            __syncthreads();
            if (srow < 16) *(short8*)&As[srow][scg] = ra;
#pragma unroll
            for (int p = 0; p < 4; ++p)
                *(short8*)&Bs[srow + p * 64][scg] = rb[p];
            __syncthreads();
            if (k0 + 64 < 256) {
                if (srow < 16) ra = loadA1(k0 + 64);
#pragma unroll
                for (int p = 0; p < 4; ++p)
                    rb[p] = *(const short8*)(Wm_b + (size_t)(srow + p * 64) * 256 + k0 + 64 + scg);
            }
#pragma unroll
            for (int ks = 0; ks < 2; ++ks) {
                short8 af = *(const short8*)&As[colL][ks * 32 + quad * 8];
#pragma unroll
                for (int j = 0; j < 2; ++j) {
                    short8 bf = *(const short8*)&Bs[nh + j * 16 + colL][ks * 32 + quad * 8];
                    acc[j] = __builtin_amdgcn_mfma_f32_16x16x32_bf16(af, bf, acc[j], 0, 0, 0);
                }
            }
        }
    }
    // LN1 stats + write m1 into Acat[:,256:512]
#pragma unroll
    for (int r = 0; r < 4; ++r) {
        float s = 0.f, q = 0.f;
#pragma unroll
        for (int j = 0; j < 2; ++j) { float v = acc[j][r]; s += v; q += v * v; }
        s += __shfl_xor(s, 1); q += __shfl_xor(q, 1);
        s += __shfl_xor(s, 2); q += __shfl_xor(q, 2);
        s += __shfl_xor(s, 4); q += __shfl_xor(q, 4);
        s += __shfl_xor(s, 8); q += __shfl_xor(q, 8);
        if (colL == 0) { stats[w][quad * 4 + r][0] = s; stats[w][quad * 4 + r][1] = q; }
    }
    __syncthreads();
#pragma unroll
    for (int r = 0; r < 4; ++r) {
        const int row = quad * 4 + r;
        float S = 0.f, Q = 0.f;
#pragma unroll
        for (int ww = 0; ww < 8; ++ww) { S += stats[ww][row][0]; Q += stats[ww][row][1]; }
        const float mean = S * (1.f / 256.f);
        const float rstd = rsqrtf(Q * (1.f / 256.f) - mean * mean + 1e-5f);
#pragma unroll
        for (int j = 0; j < 2; ++j) {
            const int col = nh + j * 16 + colL;
            Acat[row][256 + col] = __float2bfloat16((acc[j][r] - mean) * rstd * gs[col] + bs_[col]);
        }
    }
    __syncthreads();   // Acat complete; phase-1 gs reads done

    // ---- phase 2: W1 + ReLU (K=512, A from Acat), h -> Hs ----
#pragma unroll 1
    for (int nc = 0; nc < 2; ++nc) {
#pragma unroll
        for (int j = 0; j < 2; ++j) acc[j] = (f32x4){0.f, 0.f, 0.f, 0.f};
        short8 rb[4];
#pragma unroll
        for (int p = 0; p < 4; ++p)
            rb[p] = *(const short8*)(W1_b + (size_t)(nc * 256 + srow + p * 64) * 512 + scg);
        for (int k0 = 0; k0 < 512; k0 += 64) {
            __syncthreads();
#pragma unroll
            for (int p = 0; p < 4; ++p)
                *(short8*)&Bs[srow + p * 64][scg] = rb[p];
            __syncthreads();
            if (k0 + 64 < 512) {
#pragma unroll
                for (int p = 0; p < 4; ++p)
                    rb[p] = *(const short8*)(W1_b + (size_t)(nc * 256 + srow + p * 64) * 512 + k0 + 64 + scg);
            }
#pragma unroll
            for (int ks = 0; ks < 2; ++ks) {
                short8 af = *(const short8*)&Acat[colL][k0 + ks * 32 + quad * 8];
#pragma unroll
                for (int j = 0; j < 2; ++j) {
                    short8 bf = *(const short8*)&Bs[nh + j * 16 + colL][ks * 32 + quad * 8];
                    acc[j] = __builtin_amdgcn_mfma_f32_16x16x32_bf16(af, bf, acc[j], 0, 0, 0);
                }
            }
        }
#pragma unroll
        for (int r = 0; r < 4; ++r) {
            const int row = quad * 4 + r;
#pragma unroll
            for (int j = 0; j < 2; ++j) {
                const int col = nc * 256 + nh + j * 16 + colL;
                Hs[row][col] = __float2bfloat16(fmaxf(acc[j][r], 0.f));
            }
        }
    }
    if (tid < 256) { gs[tid] = g2[tid]; bs_[tid] = b2[tid]; }  // next barrier orders use
    __syncthreads();   // Hs complete

    // ---- phase 3: W2 (K=512, A from Hs) + LN2 + residual -> out ----
#pragma unroll
    for (int j = 0; j < 2; ++j) acc[j] = (f32x4){0.f, 0.f, 0.f, 0.f};
    {
        short8 rb[4];
#pragma unroll
        for (int p = 0; p < 4; ++p)
            rb[p] = *(const short8*)(W2_b + (size_t)(srow + p * 64) * 512 + scg);
        for (int k0 = 0; k0 < 512; k0 += 64) {
            __syncthreads();
#pragma unroll
            for (int p = 0; p < 4; ++p)
                *(short8*)&Bs[srow + p * 64][scg] = rb[p];
            __syncthreads();
            if (k0 + 64 < 512) {
#pragma unroll
                for (int p = 0; p < 4; ++p)
                    rb[p] = *(const short8*)(W2_b + (size_t)(srow + p * 64) * 512 + k0 + 64 + scg);
            }
#pragma unroll
            for (int ks = 0; ks < 2; ++ks) {
                short8 af = *(const short8*)&Hs[colL][k0 + ks * 32 + quad * 8];
#pragma unroll
                for (int j = 0; j < 2; ++j) {
                    short8 bf = *(const short8*)&Bs[nh + j * 16 + colL][ks * 32 + quad * 8];
                    acc[j] = __builtin_amdgcn_mfma_f32_16x16x32_bf16(af, bf, acc[j], 0, 0, 0);
                }
            }
        }
    }
#pragma unroll
    for (int r = 0; r < 4; ++r) {
        float s = 0.f, q = 0.f;
#pragma unroll
        for (int j = 0; j < 2; ++j) { float v = acc[j][r]; s += v; q += v * v; }
        s += __shfl_xor(s, 1); q += __shfl_xor(q, 1);
        s += __shfl_xor(s, 2); q += __shfl_xor(q, 2);
        s += __shfl_xor(s, 4); q += __shfl_xor(q, 4);
        s += __shfl_xor(s, 8); q += __shfl_xor(q, 8);
        if (colL == 0) { stats[w][quad * 4 + r][0] = s; stats[w][quad * 4 + r][1] = q; }
    }
    __syncthreads();
#pragma unroll
    for (int r = 0; r < 4; ++r) {
        const int row = quad * 4 + r;
        float S = 0.f, Q = 0.f;
#pragma unroll
        for (int ww = 0; ww < 8; ++ww) { S += stats[ww][row][0]; Q += stats[ww][row][1]; }
        const float mean = S * (1.f / 256.f);
        const float rstd = rsqrtf(Q * (1.f / 256.f) - mean * mean + 1e-5f);
        const size_t grow = (size_t)(m0 + row) * 256;
#pragma unroll
        for (int j = 0; j < 2; ++j) {
            const int col = nh + j * 16 + colL;
            out[grow + col] = (acc[j][r] - mean) * rstd * gs[col] + bs_[col] + x[grow + col];
        }
    }
}

// ---------------------------------------------------------------------------
extern "C" void kernel_launch(void* const* d_in, const int* in_sizes, int n_in,
                              void* d_out, int out_size, void* d_ws, size_t ws_size,
                              hipStream_t stream) {
    (void)in_sizes; (void)n_in; (void)out_size; (void)ws_size;
    const float* x   = (const float*)d_in[0];
    const float* src = (const float*)d_in[1];
    const float* F   = (const float*)d_in[2];
    const float* Wq  = (const float*)d_in[3];
    const float* Wk  = (const float*)d_in[4];
    const float* Wv  = (const float*)d_in[5];
    const float* Wm  = (const float*)d_in[6];
    const float* W1  = (const float*)d_in[7];
    const float* W2  = (const float*)d_in[8];
    const float* g1  = (const float*)d_in[9];
    const float* b1  = (const float*)d_in[10];
    const float* g2  = (const float*)d_in[11];
    const float* b2  = (const float*)d_in[12];
    float* out = (float*)d_out;

    // Workspace (24 MB):
    //   [0,2M) x_b  [2M,4M) src_b  [4M,5.25M) weights bf16
    //   [6M,8M) Qb  [8M,10M) Kb  [10M,12M) Vtb
    //   [14M,22M) Opart  [22M,22.5M) Ll
    char* ws = (char*)d_ws;
    __hip_bfloat16* x_b   = (__hip_bfloat16*)(ws);
    __hip_bfloat16* src_b = (__hip_bfloat16*)(ws + (2u << 20));
    __hip_bfloat16* Wq_b  = (__hip_bfloat16*)(ws + (4u << 20));
    __hip_bfloat16* Wk_b  = (__hip_bfloat16*)(ws + (4u << 20) + 131072);
    __hip_bfloat16* Wv_b  = (__hip_bfloat16*)(ws + (4u << 20) + 2 * 131072);
    __hip_bfloat16* Wm_b  = (__hip_bfloat16*)(ws + (4u << 20) + 3 * 131072);
    __hip_bfloat16* W1_b  = (__hip_bfloat16*)(ws + (4u << 20) + 4 * 131072);
    __hip_bfloat16* W2_b  = (__hip_bfloat16*)(ws + (4u << 20) + 4 * 131072 + 524288);
    __hip_bfloat16* Qb   = (__hip_bfloat16*)(ws + (6u << 20));
    __hip_bfloat16* Kb   = (__hip_bfloat16*)(ws + (8u << 20));
    __hip_bfloat16* Vtb  = (__hip_bfloat16*)(ws + (10u << 20));
    __hip_bfloat16* Opart = (__hip_bfloat16*)(ws + (14u << 20));
    float* Ll  = (float*)(ws + (22u << 20));

    dim3 blk(256);
    convert_all<<<dim3(2688), blk, 0, stream>>>(x, src, Wq, Wk, Wv, Wm, W1, W2,
                                                x_b, src_b, Wq_b, Wk_b, Wv_b, Wm_b, W1_b, W2_b);
    // Fused Q/K/Vt projections (Q pre-scaled by 1/sqrt(hd)); 768 real blocks
    proj_fused<<<dim3(768), blk, 0, stream>>>(x_b, src_b, Wq_b, Wk_b, Wv_b, Qb, Kb, Vtb);
    // Attention: split-S partials (round-0 proven version)
    attn_mfma<<<dim3(L_ / 64, H_, B_ * NSPLIT), blk, 0, stream>>>(Qb, Kb, Vtb, F, Opart, Ll);
    // Combine + Wm + LN1 + W1 + ReLU + W2 + LN2 + residual; 512 threads
    // (8 waves) per block for 2x latency hiding at the fixed 256-block grid
    mlp_fused<<<dim3(ML_ / 16), dim3(512), 0, stream>>>(Opart, Ll, x_b, Wm_b, W1_b, W2_b,
                                                        g1, b1, g2, b2, x, out);
}